// Round 1
// baseline (1034.172 us; speedup 1.0000x reference)
//
#include <hip/hip_runtime.h>

typedef short s16;
typedef s16 bf16x8 __attribute__((ext_vector_type(8)));   // 8 bf16 bit-patterns (4 VGPRs)
typedef float f32x4 __attribute__((ext_vector_type(4)));
typedef unsigned int u32;
typedef u32 u32x4 __attribute__((ext_vector_type(4)));
typedef unsigned short u16;

#define HSTRIDE 68   // u32 elements per LDS h-row: 16B-aligned rows, spreads banks

static_assert(sizeof(bf16x8) == 16, "frag size");

__device__ __forceinline__ float fast_tanh(float x) {
    // tanh(x) = 1 - 2/(e^{2x}+1); |err| ~ few ulp, way below bf16x3 split noise
    float e = __expf(2.0f * x);
    float r = __builtin_amdgcn_rcpf(e + 1.0f);
    return fmaf(-2.0f, r, 1.0f);
}

// round-to-nearest-even bf16 bits from fp32 (finite values only)
__device__ __forceinline__ u16 bfbits(float f) {
    u32 u = __builtin_bit_cast(u32, f);
    u32 r = (u + 0x7fffu + ((u >> 16) & 1u)) >> 16;
    return (u16)r;
}

// pack value as (hi_bf16 | lo_bf16<<16) where f ~= hi + lo
__device__ __forceinline__ u32 packsplit(float v) {
    u16 hb = bfbits(v);
    float fh = __builtin_bit_cast(float, ((u32)hb) << 16);
    u16 lb = bfbits(v - fh);
    return (u32)hb | (((u32)lb) << 16);
}

// load 8 consecutive fp32 of W row i starting at jb; emit hi/lo bf16 fragments
__device__ __forceinline__ void load_wfrag(const float* W, int ld, int i, int jb,
                                           bf16x8& hi, bf16x8& lo) {
    const float* p = W + i * ld + jb;
#pragma unroll
    for (int e = 0; e < 8; ++e) {
        float f = p[e];
        u16 hb = bfbits(f);
        float fh = __builtin_bit_cast(float, ((u32)hb) << 16);
        hi[e] = (s16)hb;
        lo[e] = (s16)bfbits(f - fh);
    }
}

// read A-fragments (hi+lo, both 32-wide k-chunks) for this lane from a packed LDS h row.
// A-layout for mfma_f32_16x16x32_bf16: lane l holds row (l&15), k = (l>>4)*8 + e.
__device__ __forceinline__ void read_afrag(const u32* row, int g, bf16x8 hi[2], bf16x8 lo[2]) {
#pragma unroll
    for (int c = 0; c < 2; ++c) {
        const u32x4* p = (const u32x4*)(row + 32 * c + 8 * g);
        u32x4 u0 = p[0];
        u32x4 u1 = p[1];
        u32x4 hw, lw;
        hw[0] = (u0[0] & 0xffffu) | (u0[1] << 16);
        hw[1] = (u0[2] & 0xffffu) | (u0[3] << 16);
        hw[2] = (u1[0] & 0xffffu) | (u1[1] << 16);
        hw[3] = (u1[2] & 0xffffu) | (u1[3] << 16);
        lw[0] = (u0[0] >> 16) | (u0[1] & 0xffff0000u);
        lw[1] = (u0[2] >> 16) | (u0[3] & 0xffff0000u);
        lw[2] = (u1[0] >> 16) | (u1[1] & 0xffff0000u);
        lw[3] = (u1[2] >> 16) | (u1[3] & 0xffff0000u);
        hi[c] = __builtin_bit_cast(bf16x8, hw);
        lo[c] = __builtin_bit_cast(bf16x8, lw);
    }
}

// 6 MFMAs per output tile: hi*hi, hi*lo, lo*hi over 2 k-chunks; acc[ti][c] are
// independent chains (spacing 4 between dependent MFMAs for latency hiding).
__device__ __forceinline__ void gemm6(f32x4 acc[2][2],
                                      const bf16x8 ah[2], const bf16x8 al[2],
                                      const bf16x8 bh[2][2], const bf16x8 bl[2][2]) {
#pragma unroll
    for (int c = 0; c < 2; ++c)
#pragma unroll
        for (int ti = 0; ti < 2; ++ti)
            acc[ti][c] = __builtin_amdgcn_mfma_f32_16x16x32_bf16(ah[c], bh[ti][c], acc[ti][c], 0, 0, 0);
#pragma unroll
    for (int c = 0; c < 2; ++c)
#pragma unroll
        for (int ti = 0; ti < 2; ++ti)
            acc[ti][c] = __builtin_amdgcn_mfma_f32_16x16x32_bf16(ah[c], bl[ti][c], acc[ti][c], 0, 0, 0);
#pragma unroll
    for (int c = 0; c < 2; ++c)
#pragma unroll
        for (int ti = 0; ti < 2; ++ti)
            acc[ti][c] = __builtin_amdgcn_mfma_f32_16x16x32_bf16(al[c], bh[ti][c], acc[ti][c], 0, 0, 0);
}

__global__ __launch_bounds__(128, 1)
void rnn3_fused(const float* __restrict__ x,
                const float* __restrict__ wih0, const float* __restrict__ whh0,
                const float* __restrict__ bih0, const float* __restrict__ bhh0,
                const float* __restrict__ wih1, const float* __restrict__ whh1,
                const float* __restrict__ bih1, const float* __restrict__ bhh1,
                const float* __restrict__ wih2, const float* __restrict__ whh2,
                const float* __restrict__ bih2, const float* __restrict__ bhh2,
                const float* __restrict__ w1, const float* __restrict__ bf1,
                const float* __restrict__ w2, const float* __restrict__ bf2,
                const float* __restrict__ w3, const float* __restrict__ bf3,
                float* __restrict__ out)
{
    // packed (hi|lo) bf16 h-state for h0,h1,h2: [which][row][col(+pad)]
    __shared__ __align__(16) u32 hp[3][16][HSTRIDE];
    __shared__ float hf[16][65];    // final h2 fp32
    __shared__ float a1s[16][33];   // head stage 1 (32 used)
    __shared__ float a2s[16][17];   // head stage 2 (16 used)

    const int tid = (int)threadIdx.x;
    const int l = tid & 63;         // lane
    const int wv = tid >> 6;        // wave 0/1 -> i-tiles {0,1} / {2,3}
    const int m = l & 15;
    const int g = l >> 4;           // 0..3
    const int blk = (int)blockIdx.x;

    // ---- stage weights into registers (one-time) ----
    bf16x8 W0h[2][2], W0l[2][2];       // w_hh0^T fragments
    bf16x8 W1ihh[2][2], W1ihl[2][2];   // w_ih1^T
    bf16x8 W1hhh[2][2], W1hhl[2][2];   // w_hh1^T
    bf16x8 W2ihh[2][2], W2ihl[2][2];   // w_ih2^T
    bf16x8 W2hhh[2][2], W2hhl[2][2];   // w_hh2^T
    float w0r[2][4];
    float b0s[2], b1s[2], b2s[2];

#pragma unroll
    for (int ti = 0; ti < 2; ++ti) {
        int i = (wv * 2 + ti) * 16 + m;    // output column this lane owns (B-frag n = l&15)
#pragma unroll
        for (int c = 0; c < 2; ++c) {
            int jb = 32 * c + 8 * g;       // B-frag k = (l>>4)*8 + e within chunk
            load_wfrag(whh0, 64, i, jb, W0h[ti][c], W0l[ti][c]);
            load_wfrag(wih1, 64, i, jb, W1ihh[ti][c], W1ihl[ti][c]);
            load_wfrag(whh1, 64, i, jb, W1hhh[ti][c], W1hhl[ti][c]);
            load_wfrag(wih2, 64, i, jb, W2ihh[ti][c], W2ihl[ti][c]);
            load_wfrag(whh2, 64, i, jb, W2hhh[ti][c], W2hhl[ti][c]);
        }
#pragma unroll
        for (int j = 0; j < 4; ++j) w0r[ti][j] = wih0[i * 4 + j];
        b0s[ti] = bih0[i] + bhh0[i];
        b1s[ti] = bih1[i] + bhh1[i];
        b2s[ti] = bih2[i] + bhh2[i];
    }

    // A-fragment caches for h0,h1,h2 (zero initial state)
    bf16x8 aH0h[2], aH0l[2], aH1h[2], aH1l[2], aH2h[2], aH2l[2];
#pragma unroll
    for (int c = 0; c < 2; ++c)
#pragma unroll
        for (int e = 0; e < 8; ++e) {
            aH0h[c][e] = 0; aH0l[c][e] = 0;
            aH1h[c][e] = 0; aH1l[c][e] = 0;
            aH2h[c][e] = 0; aH2l[c][e] = 0;
        }

    const float4* xv = (const float4*)x;   // x[b][t][0..3] is one float4
    int xrow[4];
#pragma unroll
    for (int q = 0; q < 4; ++q) xrow[q] = (blk * 16 + g * 4 + q) * 512;

    float4 xn[4];
#pragma unroll
    for (int q = 0; q < 4; ++q) xn[q] = xv[xrow[q]];   // t=0

    float h2v[2][4];

#pragma unroll 1
    for (int t = 0; t < 512; ++t) {
        float4 xc[4];
#pragma unroll
        for (int q = 0; q < 4; ++q) xc[q] = xn[q];
        int tn = (t + 1) & 511;            // wraps to 0 at end (valid dummy read)
#pragma unroll
        for (int q = 0; q < 4; ++q) xn[q] = xv[xrow[q] + tn];

        // ---------- layer 0 ----------
        f32x4 acc[2][2];
#pragma unroll
        for (int ti = 0; ti < 2; ++ti) {
            acc[ti][0] = (f32x4){b0s[ti], b0s[ti], b0s[ti], b0s[ti]};
            acc[ti][1] = (f32x4){0.f, 0.f, 0.f, 0.f};
        }
        gemm6(acc, aH0h, aH0l, W0h, W0l);
#pragma unroll
        for (int ti = 0; ti < 2; ++ti)
#pragma unroll
            for (int q = 0; q < 4; ++q) {
                float s = acc[ti][0][q] + acc[ti][1][q];
                s = fmaf(xc[q].x, w0r[ti][0], s);
                s = fmaf(xc[q].y, w0r[ti][1], s);
                s = fmaf(xc[q].z, w0r[ti][2], s);
                s = fmaf(xc[q].w, w0r[ti][3], s);
                float h = fast_tanh(s);
                hp[0][g * 4 + q][(wv * 2 + ti) * 16 + m] = packsplit(h);
            }
        __syncthreads();
        read_afrag(&hp[0][m][0], g, aH0h, aH0l);   // h0_t: used by L1-ih now and L0-hh next step

        // ---------- layer 1 ----------
#pragma unroll
        for (int ti = 0; ti < 2; ++ti) {
            acc[ti][0] = (f32x4){b1s[ti], b1s[ti], b1s[ti], b1s[ti]};
            acc[ti][1] = (f32x4){0.f, 0.f, 0.f, 0.f};
        }
        gemm6(acc, aH0h, aH0l, W1ihh, W1ihl);      // input part: h0_t
        gemm6(acc, aH1h, aH1l, W1hhh, W1hhl);      // recurrent part: h1_{t-1}
#pragma unroll
        for (int ti = 0; ti < 2; ++ti)
#pragma unroll
            for (int q = 0; q < 4; ++q) {
                float h = fast_tanh(acc[ti][0][q] + acc[ti][1][q]);
                hp[1][g * 4 + q][(wv * 2 + ti) * 16 + m] = packsplit(h);
            }
        __syncthreads();
        read_afrag(&hp[1][m][0], g, aH1h, aH1l);   // h1_t

        // ---------- layer 2 ----------
#pragma unroll
        for (int ti = 0; ti < 2; ++ti) {
            acc[ti][0] = (f32x4){b2s[ti], b2s[ti], b2s[ti], b2s[ti]};
            acc[ti][1] = (f32x4){0.f, 0.f, 0.f, 0.f};
        }
        gemm6(acc, aH1h, aH1l, W2ihh, W2ihl);      // input part: h1_t
        gemm6(acc, aH2h, aH2l, W2hhh, W2hhl);      // recurrent part: h2_{t-1}
#pragma unroll
        for (int ti = 0; ti < 2; ++ti)
#pragma unroll
            for (int q = 0; q < 4; ++q) {
                float h = fast_tanh(acc[ti][0][q] + acc[ti][1][q]);
                h2v[ti][q] = h;
                hp[2][g * 4 + q][(wv * 2 + ti) * 16 + m] = packsplit(h);
            }
        __syncthreads();
        read_afrag(&hp[2][m][0], g, aH2h, aH2l);   // h2_t
    }

    // ---------- MLP head (fp32, one-time) ----------
#pragma unroll
    for (int ti = 0; ti < 2; ++ti)
#pragma unroll
        for (int q = 0; q < 4; ++q)
            hf[g * 4 + q][(wv * 2 + ti) * 16 + m] = h2v[ti][q];
    __syncthreads();

    {   // stage 1: [16x64] @ w1^T -> relu -> [16x32]
        int r = tid & 15, oq = tid >> 4;   // oq 0..7
#pragma unroll
        for (int k = 0; k < 4; ++k) {
            int o = oq * 4 + k;
            float s = bf1[o];
            for (int j = 0; j < 64; ++j) s = fmaf(hf[r][j], w1[o * 64 + j], s);
            a1s[r][o] = fmaxf(s, 0.f);
        }
    }
    __syncthreads();
    {   // stage 2: [16x32] @ w2^T -> [16x16]
        int r = tid & 15, oq = tid >> 4;
#pragma unroll
        for (int k = 0; k < 2; ++k) {
            int o = oq * 2 + k;
            float s = bf2[o];
            for (int j = 0; j < 32; ++j) s = fmaf(a1s[r][j], w2[o * 32 + j], s);
            a2s[r][o] = s;
        }
    }
    __syncthreads();
    if (tid < 16) {   // stage 3: [16x16] @ w3^T -> [16]
        float s = bf3[0];
        for (int j = 0; j < 16; ++j) s = fmaf(a2s[tid][j], w3[j], s);
        out[blk * 16 + tid] = s;
    }
}

extern "C" void kernel_launch(void* const* d_in, const int* in_sizes, int n_in,
                              void* d_out, int out_size, void* d_ws, size_t ws_size,
                              hipStream_t stream) {
    const float* x    = (const float*)d_in[0];
    const float* wih0 = (const float*)d_in[1];
    const float* whh0 = (const float*)d_in[2];
    const float* bih0 = (const float*)d_in[3];
    const float* bhh0 = (const float*)d_in[4];
    const float* wih1 = (const float*)d_in[5];
    const float* whh1 = (const float*)d_in[6];
    const float* bih1 = (const float*)d_in[7];
    const float* bhh1 = (const float*)d_in[8];
    const float* wih2 = (const float*)d_in[9];
    const float* whh2 = (const float*)d_in[10];
    const float* bih2 = (const float*)d_in[11];
    const float* bhh2 = (const float*)d_in[12];
    const float* w1   = (const float*)d_in[13];
    const float* bf1  = (const float*)d_in[14];
    const float* w2   = (const float*)d_in[15];
    const float* bf2  = (const float*)d_in[16];
    const float* w3   = (const float*)d_in[17];
    const float* bf3  = (const float*)d_in[18];

    rnn3_fused<<<dim3(256), dim3(128), 0, stream>>>(
        x, wih0, whh0, bih0, bhh0, wih1, whh1, bih1, bhh1,
        wih2, whh2, bih2, bhh2, w1, bf1, w2, bf2, w3, bf3,
        (float*)d_out);
}

// Round 6
// 578.330 us; speedup vs baseline: 1.7882x; 1.7882x over previous
//
#include <hip/hip_runtime.h>

typedef short s16;
typedef s16 bf16x8 __attribute__((ext_vector_type(8)));   // 8 bf16 bit patterns = 4 VGPRs
typedef float f32x4 __attribute__((ext_vector_type(4)));
typedef unsigned int u32;
typedef unsigned short u16;

#define HST 72   // u16 elements per LDS h-row (144 B): 8B/16B aligned, low conflict

__device__ __forceinline__ float fast_tanh(float x) {
    // tanh(x) = 1 - 2/(e^{2x}+1); error ~ulp, far below bf16x3 split noise
    float e = __expf(2.0f * x);
    float r = __builtin_amdgcn_rcpf(e + 1.0f);
    return fmaf(-2.0f, r, 1.0f);
}

// round-to-nearest-even bf16 bits from fp32 (finite only)
__device__ __forceinline__ u16 bfbits(float f) {
    u32 u = __builtin_bit_cast(u32, f);
    return (u16)((u + 0x7fffu + ((u >> 16) & 1u)) >> 16);
}

// A-fragment loader: row i (neuron), 8 consecutive k starting at jb; hi/lo split.
// A layout (16x16x32): lane holds row m=l&15, k=(l>>4)*8+e (+32 per chunk).
__device__ __forceinline__ void load_wfrag(const float* W, int i, int jb, bf16x8& hi, bf16x8& lo) {
    const float* p = W + i * 64 + jb;
#pragma unroll
    for (int e = 0; e < 8; ++e) {
        float f = p[e];
        u16 hb = bfbits(f);
        float fh = __builtin_bit_cast(float, ((u32)hb) << 16);
        hi[e] = (s16)hb;
        lo[e] = (s16)bfbits(f - fh);
    }
}

// one 16x16 output tile, K=64 as 2 chunks, 3-product split: Wh*hh + Wh*hl + Wl*hh
__device__ __forceinline__ void mm3(f32x4 acc[2], const bf16x8 wh[2], const bf16x8 wl[2],
                                    const bf16x8 bh[2], const bf16x8 bl[2]) {
#pragma unroll
    for (int c = 0; c < 2; ++c)
        acc[c] = __builtin_amdgcn_mfma_f32_16x16x32_bf16(wh[c], bh[c], acc[c], 0, 0, 0);
#pragma unroll
    for (int c = 0; c < 2; ++c)
        acc[c] = __builtin_amdgcn_mfma_f32_16x16x32_bf16(wh[c], bl[c], acc[c], 0, 0, 0);
#pragma unroll
    for (int c = 0; c < 2; ++c)
        acc[c] = __builtin_amdgcn_mfma_f32_16x16x32_bf16(wl[c], bh[c], acc[c], 0, 0, 0);
}

// split 4 h values (4 consecutive neurons) into hi/lo bf16 and write 2x ds_write_b64
__device__ __forceinline__ void store_h(u16* hi_row, u16* lo_row, int nb, const float h[4]) {
    u16 hb[4], lb[4];
#pragma unroll
    for (int r = 0; r < 4; ++r) {
        hb[r] = bfbits(h[r]);
        float fh = __builtin_bit_cast(float, ((u32)hb[r]) << 16);
        lb[r] = bfbits(h[r] - fh);
    }
    uint2 hv, lv;
    hv.x = (u32)hb[0] | ((u32)hb[1] << 16);
    hv.y = (u32)hb[2] | ((u32)hb[3] << 16);
    lv.x = (u32)lb[0] | ((u32)lb[1] << 16);
    lv.y = (u32)lb[2] | ((u32)lb[3] << 16);
    *(uint2*)(hi_row + nb) = hv;
    *(uint2*)(lo_row + nb) = lv;
}

// B-fragment read: col n=batch=l&15 (row pointer), k=32c+8g+e — contiguous b128, no unpack
__device__ __forceinline__ void read_bfrag(const u16* hi_row, const u16* lo_row, int g,
                                           bf16x8 bh[2], bf16x8 bl[2]) {
#pragma unroll
    for (int c = 0; c < 2; ++c) {
        bh[c] = *(const bf16x8*)(hi_row + 32 * c + 8 * g);
        bl[c] = *(const bf16x8*)(lo_row + 32 * c + 8 * g);
    }
}

__global__ __launch_bounds__(256, 1)
void rnn3_fused(const float* __restrict__ x,
                const float* __restrict__ wih0, const float* __restrict__ whh0,
                const float* __restrict__ bih0, const float* __restrict__ bhh0,
                const float* __restrict__ wih1, const float* __restrict__ whh1,
                const float* __restrict__ bih1, const float* __restrict__ bhh1,
                const float* __restrict__ wih2, const float* __restrict__ whh2,
                const float* __restrict__ bih2, const float* __restrict__ bhh2,
                const float* __restrict__ w1, const float* __restrict__ bf1,
                const float* __restrict__ w2, const float* __restrict__ bf2,
                const float* __restrict__ w3, const float* __restrict__ bf3,
                float* __restrict__ out)
{
    // h state, separate hi/lo bf16 arrays: [layer][batch][neuron]
    __shared__ __align__(16) u16 Hhi[3][16][HST];
    __shared__ __align__(16) u16 Hlo[3][16][HST];
    __shared__ float hf[16][65];    // final h2 fp32
    __shared__ float a1s[16][33];   // head stage 1
    __shared__ float a2s[16][17];   // head stage 2

    const int tid = (int)threadIdx.x;
    const int l = tid & 63;
    const int wv = tid >> 6;        // wave 0..3 owns neurons wv*16..wv*16+15
    const int ml = l & 15;
    const int g = l >> 4;           // 0..3
    const int blk = (int)blockIdx.x;
    const int nb = wv * 16 + 4 * g; // this thread's 4 neurons: nb..nb+3

    // ---- weight A-fragments (one-time, registers) ----
    bf16x8 W0h[2], W0l[2], I1h[2], I1l[2], H1h[2], H1l[2], I2h[2], I2l[2], H2h[2], H2l[2];
    {
        int arow = wv * 16 + ml;    // neuron row for A-frag
#pragma unroll
        for (int c = 0; c < 2; ++c) {
            int jb = 32 * c + 8 * g;
            load_wfrag(whh0, arow, jb, W0h[c], W0l[c]);
            load_wfrag(wih1, arow, jb, I1h[c], I1l[c]);
            load_wfrag(whh1, arow, jb, H1h[c], H1l[c]);
            load_wfrag(wih2, arow, jb, I2h[c], I2l[c]);
            load_wfrag(whh2, arow, jb, H2h[c], H2l[c]);
        }
    }
    float w0r[4][4], b0[4], b1[4], b2[4];
#pragma unroll
    for (int r = 0; r < 4; ++r) {
        int n = nb + r;
#pragma unroll
        for (int j = 0; j < 4; ++j) w0r[r][j] = wih0[n * 4 + j];
        b0[r] = bih0[n] + bhh0[n];
        b1[r] = bih1[n] + bhh1[n];
        b2[r] = bih2[n] + bhh2[n];
    }

    // B-fragment caches (h0,h1,h2), zero initial state
    bf16x8 B0h[2], B0l[2], B1h[2], B1l[2], B2h[2], B2l[2];
#pragma unroll
    for (int c = 0; c < 2; ++c)
#pragma unroll
        for (int e = 0; e < 8; ++e) {
            B0h[c][e] = 0; B0l[c][e] = 0;
            B1h[c][e] = 0; B1l[c][e] = 0;
            B2h[c][e] = 0; B2l[c][e] = 0;
        }

    const float4* xv = (const float4*)x;
    const long xrow = (long)(blk * 16 + ml) * 512;   // this thread's batch row
    float4 xn = xv[xrow];                            // t=0 prefetch

    float h2v[4];

#pragma unroll 1
    for (int t = 0; t < 512; ++t) {
        float4 xc = xn;
        xn = xv[xrow + ((t + 1) & 511)];             // prefetch next (wrap read harmless)

        // ---- all three recurrent GEMMs up-front (depend only on t-1 state) ----
        f32x4 a0[2], a1[2], a2[2];
        a0[0] = (f32x4){b0[0], b0[1], b0[2], b0[3]}; a0[1] = (f32x4){0.f, 0.f, 0.f, 0.f};
        a1[0] = (f32x4){b1[0], b1[1], b1[2], b1[3]}; a1[1] = (f32x4){0.f, 0.f, 0.f, 0.f};
        a2[0] = (f32x4){b2[0], b2[1], b2[2], b2[3]}; a2[1] = (f32x4){0.f, 0.f, 0.f, 0.f};
        mm3(a0, W0h, W0l, B0h, B0l);   // Whh0 * h0(t-1)
        mm3(a1, H1h, H1l, B1h, B1l);   // Whh1 * h1(t-1)
        mm3(a2, H2h, H2l, B2h, B2l);   // Whh2 * h2(t-1)

        float hL[4];
        // ---- layer 0 finish: + x part (K=4, VALU) ----
#pragma unroll
        for (int r = 0; r < 4; ++r) {
            float s = a0[0][r] + a0[1][r];
            s = fmaf(xc.x, w0r[r][0], s);
            s = fmaf(xc.y, w0r[r][1], s);
            s = fmaf(xc.z, w0r[r][2], s);
            s = fmaf(xc.w, w0r[r][3], s);
            hL[r] = fast_tanh(s);
        }
        store_h(&Hhi[0][ml][0], &Hlo[0][ml][0], nb, hL);
        __syncthreads();
        read_bfrag(&Hhi[0][ml][0], &Hlo[0][ml][0], g, B0h, B0l);   // h0(t)

        // ---- layer 1 ----
        mm3(a1, I1h, I1l, B0h, B0l);   // + Wih1 * h0(t)
#pragma unroll
        for (int r = 0; r < 4; ++r) hL[r] = fast_tanh(a1[0][r] + a1[1][r]);
        store_h(&Hhi[1][ml][0], &Hlo[1][ml][0], nb, hL);
        __syncthreads();
        read_bfrag(&Hhi[1][ml][0], &Hlo[1][ml][0], g, B1h, B1l);   // h1(t)

        // ---- layer 2 ----
        mm3(a2, I2h, I2l, B1h, B1l);   // + Wih2 * h1(t)
#pragma unroll
        for (int r = 0; r < 4; ++r) { hL[r] = fast_tanh(a2[0][r] + a2[1][r]); h2v[r] = hL[r]; }
        store_h(&Hhi[2][ml][0], &Hlo[2][ml][0], nb, hL);
        __syncthreads();
        read_bfrag(&Hhi[2][ml][0], &Hlo[2][ml][0], g, B2h, B2l);   // h2(t)
    }

    // ---------- MLP head (fp32, one-time) ----------
#pragma unroll
    for (int r = 0; r < 4; ++r) hf[ml][nb + r] = h2v[r];
    __syncthreads();

    {   // stage 1: [16x64] @ w1^T -> relu -> [16x32]; 256 threads, 2 outputs each
        int r = tid & 15, o2 = tid >> 4;   // o2 0..15
#pragma unroll
        for (int k = 0; k < 2; ++k) {
            int o = o2 * 2 + k;
            float s = bf1[o];
            for (int j = 0; j < 64; ++j) s = fmaf(hf[r][j], w1[o * 64 + j], s);
            a1s[r][o] = fmaxf(s, 0.f);
        }
    }
    __syncthreads();
    {   // stage 2: [16x32] @ w2^T -> [16x16]; one output each
        int r = tid & 15, o = tid >> 4;
        float s = bf2[o];
        for (int j = 0; j < 32; ++j) s = fmaf(a1s[r][j], w2[o * 32 + j], s);
        a2s[r][o] = s;
    }
    __syncthreads();
    if (tid < 16) {   // stage 3: [16x16] @ w3^T -> [16]
        float s = bf3[0];
        for (int j = 0; j < 16; ++j) s = fmaf(a2s[tid][j], w3[j], s);
        out[blk * 16 + tid] = s;
    }
}

extern "C" void kernel_launch(void* const* d_in, const int* in_sizes, int n_in,
                              void* d_out, int out_size, void* d_ws, size_t ws_size,
                              hipStream_t stream) {
    const float* x    = (const float*)d_in[0];
    const float* wih0 = (const float*)d_in[1];
    const float* whh0 = (const float*)d_in[2];
    const float* bih0 = (const float*)d_in[3];
    const float* bhh0 = (const float*)d_in[4];
    const float* wih1 = (const float*)d_in[5];
    const float* whh1 = (const float*)d_in[6];
    const float* bih1 = (const float*)d_in[7];
    const float* bhh1 = (const float*)d_in[8];
    const float* wih2 = (const float*)d_in[9];
    const float* whh2 = (const float*)d_in[10];
    const float* bih2 = (const float*)d_in[11];
    const float* bhh2 = (const float*)d_in[12];
    const float* w1   = (const float*)d_in[13];
    const float* bf1  = (const float*)d_in[14];
    const float* w2   = (const float*)d_in[15];
    const float* bf2  = (const float*)d_in[16];
    const float* w3   = (const float*)d_in[17];
    const float* bf3  = (const float*)d_in[18];

    rnn3_fused<<<dim3(256), dim3(256), 0, stream>>>(
        x, wih0, whh0, bih0, bhh0, wih1, whh1, bih1, bhh1,
        wih2, whh2, bih2, bhh2, w1, bf1, w2, bf2, w3, bf3,
        (float*)d_out);
}